// Round 8
// baseline (273.825 us; speedup 1.0000x reference)
//
#include <hip/hip_runtime.h>
#include <hip/hip_bf16.h>
#include <hip/hip_fp16.h>
#include <math.h>

// GCN link prediction. R19 discriminating round:
//  (a) pSortG = chunk sort (blocks < CN) + UNSCALED gemm1 (blocks >= CN) in
//      one launch: the 51MB x-stream overlaps the latency-bound sort blocks.
//  (b) pS2G slim: in-bucket counting sort (register-cached) + dinv + CSR
//      start + dinv-scaling of the bucket's own ts1h rows (4KB sequential).
//  (c) pGat1/pGat2: 2 lanes/node x uint4 loads x 16-deep unroll, 512-thread
//      blocks -> 4x fewer scattered lane-requests than R11 AND 2x the
//      per-lane MLP of R12 (distinguishes TA-throughput vs latency floor).
//   deg[v] = incount(col==v)+1 ; dinv = rsqrt(deg)
//   ts[v]  = (h[v]@W)*dinv[v]          (fp16 gather tables, L2-resident)
//   h'[c]  = act(dinv[c]*(sum_{e:col=c} ts[row_e] + ts[c]) + b)
//   score  = sigmoid(dot(h2[row], h2[col]))

#define BSH 7
#define BSZ 128            // nodes per bucket -> NBUK = 782 (<= 1024)
#define CAPB 8192          // slots per bucket (2x avg 4092; +60 sigma)
#define RCAP 12            // edge register cache per thread in pS2G (512 thr)
#define MAXCH 3200         // edges per chunk (multiple of 4)
#define MAXCHUNKS 1024

// ---- pSortG: role-split launch. Sort blocks: chunk histogram -> atomic base
//      grab -> LDS bucket-order -> run writes. Gemm blocks: ts[v]=half(x@W1),
//      UNSCALED (dinv applied later in pS2G). ----
__global__ __launch_bounds__(1024) void pSortG(
    const int* __restrict__ row, const int* __restrict__ col,
    int* __restrict__ gcur, unsigned int* __restrict__ ebuf,
    const float* __restrict__ x, const float* __restrict__ W1,
    __half* __restrict__ ts, int E, int CH, int NBUK, int N, int CN) {
    __shared__ unsigned int se[MAXCH];        // chunk edges, bucket-ordered
    __shared__ unsigned short pk[MAXCH];      // bucket id per LDS slot
    __shared__ int lhist[1024], lbase[1024], lcur[1024], gbase[1024];
    __shared__ float wsT[16 * 132];
    const int t = threadIdx.x;
    if (blockIdx.x >= CN) {
        // ---- gemm role: 1 node/thread, unscaled ----
        const int b = blockIdx.x - CN;
        for (int idx = t; idx < 2048; idx += 1024) {
            int kk = idx >> 4, c = idx & 15;
            wsT[c * 132 + kk] = W1[idx];
        }
        __syncthreads();
        const int n = b * 1024 + t;
        if (n >= N) return;
        const float4* xr = (const float4*)(x + (size_t)n * 128);
        float acc[16];
        #pragma unroll
        for (int c = 0; c < 16; ++c) acc[c] = 0.f;
        #pragma unroll 4
        for (int k4 = 0; k4 < 32; ++k4) {
            float4 a = xr[k4];
            #pragma unroll
            for (int c = 0; c < 16; ++c) {
                const float4 w = *(const float4*)&wsT[c * 132 + k4 * 4];
                acc[c] = fmaf(a.x, w.x, fmaf(a.y, w.y, fmaf(a.z, w.z, fmaf(a.w, w.w, acc[c]))));
            }
        }
        union { __half h[16]; uint4 u[2]; } o;
        #pragma unroll
        for (int c = 0; c < 16; ++c) o.h[c] = __float2half(acc[c]);
        uint4* dst = (uint4*)(ts + (size_t)n * 16);
        dst[0] = o.u[0]; dst[1] = o.u[1];
        return;
    }
    // ---- sort role ----
    const int b = blockIdx.x;
    lhist[t] = 0;
    __syncthreads();
    const int s = b * CH, e = min(E, s + CH);
    const int cnt = e - s;
    const int n4 = cnt >> 2;
    const int4* c4 = (const int4*)(col + s);
    const int4* r4 = (const int4*)(row + s);
    for (int i = t; i < n4; i += 1024) {
        int4 c = c4[i];
        atomicAdd(&lhist[c.x >> BSH], 1);
        atomicAdd(&lhist[c.y >> BSH], 1);
        atomicAdd(&lhist[c.z >> BSH], 1);
        atomicAdd(&lhist[c.w >> BSH], 1);
    }
    for (int i = (n4 << 2) + t; i < cnt; i += 1024) atomicAdd(&lhist[col[s + i] >> BSH], 1);
    __syncthreads();
    {   // 1024-wide exclusive scan of lhist -> lbase (scratch in lcur)
        int own = lhist[t];
        lcur[t] = own;
        __syncthreads();
        for (int d = 1; d < 1024; d <<= 1) {
            int add = (t >= d) ? lcur[t - d] : 0;
            __syncthreads();
            lcur[t] += add;
            __syncthreads();
        }
        lbase[t] = lcur[t] - own;
        lcur[t] = lbase[t];
        __syncthreads();
        if (t < NBUK) {   // grab this chunk's range in bucket t
            int base = atomicAdd(&gcur[t], lhist[t]);
            gbase[t] = t * CAPB + base - lbase[t];
        }
    }
    __syncthreads();
    // placement into LDS (bucket-ordered)
    for (int i = t; i < n4; i += 1024) {
        int4 c = c4[i];
        int4 r = r4[i];
        int k0 = c.x >> BSH, p0 = atomicAdd(&lcur[k0], 1);
        se[p0] = ((unsigned int)(c.x & (BSZ - 1)) << 17) | (unsigned int)r.x; pk[p0] = (unsigned short)k0;
        int k1 = c.y >> BSH, p1 = atomicAdd(&lcur[k1], 1);
        se[p1] = ((unsigned int)(c.y & (BSZ - 1)) << 17) | (unsigned int)r.y; pk[p1] = (unsigned short)k1;
        int k2 = c.z >> BSH, p2 = atomicAdd(&lcur[k2], 1);
        se[p2] = ((unsigned int)(c.z & (BSZ - 1)) << 17) | (unsigned int)r.z; pk[p2] = (unsigned short)k2;
        int k3 = c.w >> BSH, p3 = atomicAdd(&lcur[k3], 1);
        se[p3] = ((unsigned int)(c.w & (BSZ - 1)) << 17) | (unsigned int)r.w; pk[p3] = (unsigned short)k3;
    }
    for (int i = (n4 << 2) + t; i < cnt; i += 1024) {
        int c = col[s + i], r = row[s + i];
        int k = c >> BSH, p = atomicAdd(&lcur[k], 1);
        se[p] = ((unsigned int)(c & (BSZ - 1)) << 17) | (unsigned int)r; pk[p] = (unsigned short)k;
    }
    __syncthreads();
    // write-out: consecutive LDS slots in a bucket -> consecutive global
    for (int i = t; i < cnt; i += 1024) {
        int k = pk[i];
        ebuf[gbase[k] + i] = se[i];
    }
}

// ---- pS2G: in-bucket counting sort (register-cached) -> dinv + CSR start;
//      epilogue scales this bucket's ts1h rows by dinv (sequential 4KB) ----
__global__ __launch_bounds__(512) void pS2G(
    const unsigned int* __restrict__ ebuf, const int* __restrict__ gcur,
    unsigned int* __restrict__ ebuf2, float* __restrict__ dinv,
    int* __restrict__ start, __half* __restrict__ ts, int N) {
    __shared__ int h[BSZ], sc[BSZ], cur[BSZ];
    const int t = threadIdx.x, k = blockIdx.x;
    if (t < BSZ) h[t] = 0;
    __syncthreads();
    const int s = k * CAPB, e = s + gcur[k];
    const int cnt = e - s;
    unsigned int r[RCAP];
    const bool fits = (cnt <= 512 * RCAP);
    if (fits) {
        int nr = 0;
        for (int i = s + t; i < e; i += 512) {
            unsigned int w = ebuf[i];
            r[nr++] = w;
            atomicAdd(&h[w >> 17], 1);
        }
    } else {
        for (int i = s + t; i < e; i += 512) atomicAdd(&h[ebuf[i] >> 17], 1);
    }
    __syncthreads();
    if (t < BSZ) sc[t] = h[t];
    __syncthreads();
    for (int d = 1; d < BSZ; d <<= 1) {
        int add = (t < BSZ && t >= d) ? sc[t - d] : 0;
        __syncthreads();
        if (t < BSZ) sc[t] += add;
        __syncthreads();
    }
    if (t < BSZ) {
        cur[t] = sc[t] - h[t];             // exclusive scan
        const int v = (k << BSH) + t;
        if (v < N) {
            dinv[v] = rsqrtf((float)h[t] + 1.0f);
            start[v] = s + cur[t];
        }
    }
    __syncthreads();
    if (fits) {
        int nr = 0;
        for (int i = s + t; i < e; i += 512) {
            unsigned int w = r[nr++];
            int p = atomicAdd(&cur[w >> 17], 1);
            ebuf2[s + p] = w;
        }
    } else {
        for (int i = s + t; i < e; i += 512) {
            unsigned int w = ebuf[i];
            int p = atomicAdd(&cur[w >> 17], 1);
            ebuf2[s + p] = w;
        }
    }
    // ---- scale ts rows of this bucket: 4 threads/node, uint2 (8B) each ----
    const int u = t >> 2, q = t & 3;
    const int v = (k << BSH) + u;
    if (v >= N) return;
    const float dv = rsqrtf((float)h[u] + 1.0f);
    uint2* p2 = (uint2*)(ts + (size_t)v * 16) + q;
    uint2 w2 = *p2;
    __half2 a = *(__half2*)&w2.x, b = *(__half2*)&w2.y;
    float2 fa = __half22float2(a), fb = __half22float2(b);
    *(__half2*)&w2.x = __floats2half2_rn(fa.x * dv, fa.y * dv);
    *(__half2*)&w2.y = __floats2half2_rn(fb.x * dv, fb.y * dv);
    *p2 = w2;
}

// Unpack-accumulate one uint4 (8 halves) into 8 fp32 channel accumulators.
#define ACC8(qq) do {                                        \
    float2 f_;                                               \
    f_ = __half22float2(*(const __half2*)&(qq).x); a0 += f_.x; a1 += f_.y; \
    f_ = __half22float2(*(const __half2*)&(qq).y); a2 += f_.x; a3 += f_.y; \
    f_ = __half22float2(*(const __half2*)&(qq).z); a4 += f_.x; a5 += f_.y; \
    f_ = __half22float2(*(const __half2*)&(qq).w); a6 += f_.x; a7 += f_.y; \
} while (0)

#define GLD(j) tsq[((size_t)(ebuf2[i + (j)] & 0x1FFFF) << 1) + p]

// ---- Layer-1 aggregation: 2 lanes/node, uint4 loads, 16-deep unroll;
//      fused bias/ReLU + 16x16 W2 via one xor-shuffle pair exchange ----
__global__ __launch_bounds__(512) void pGat1(
    const unsigned int* __restrict__ ebuf2, const int* __restrict__ start,
    const int* __restrict__ gcur,
    const uint4* __restrict__ tsq, const float* __restrict__ dinv,
    const float* __restrict__ b1, const float* __restrict__ W2,
    uint4* __restrict__ ts2q, int N) {
    __shared__ float w2s[256];
    const int tid = threadIdx.x;
    if (tid < 256) w2s[tid] = W2[tid];
    __syncthreads();
    const int p = tid & 1;                 // half: channels 8p..8p+7
    const int v = blockIdx.x * 256 + (tid >> 1);
    if (v >= N) return;
    const int s = start[v];
    const int k = v >> BSH;
    const bool lastv = (((v + 1) & (BSZ - 1)) == 0) || (v + 1 >= N);
    const int e = lastv ? (k * CAPB + gcur[k]) : start[v + 1];
    float a0 = 0.f, a1 = 0.f, a2 = 0.f, a3 = 0.f, a4 = 0.f, a5 = 0.f, a6 = 0.f, a7 = 0.f;
    int i = s;
    for (; i + 16 <= e; i += 16) {
        uint4 q0 = GLD(0),  q1 = GLD(1),  q2 = GLD(2),  q3 = GLD(3);
        uint4 q4 = GLD(4),  q5 = GLD(5),  q6 = GLD(6),  q7 = GLD(7);
        uint4 q8 = GLD(8),  q9 = GLD(9),  qa = GLD(10), qb = GLD(11);
        uint4 qc = GLD(12), qd = GLD(13), qe = GLD(14), qf = GLD(15);
        ACC8(q0); ACC8(q1); ACC8(q2); ACC8(q3);
        ACC8(q4); ACC8(q5); ACC8(q6); ACC8(q7);
        ACC8(q8); ACC8(q9); ACC8(qa); ACC8(qb);
        ACC8(qc); ACC8(qd); ACC8(qe); ACC8(qf);
    }
    for (; i + 8 <= e; i += 8) {
        uint4 q0 = GLD(0), q1 = GLD(1), q2 = GLD(2), q3 = GLD(3);
        uint4 q4 = GLD(4), q5 = GLD(5), q6 = GLD(6), q7 = GLD(7);
        ACC8(q0); ACC8(q1); ACC8(q2); ACC8(q3);
        ACC8(q4); ACC8(q5); ACC8(q6); ACC8(q7);
    }
    for (; i + 4 <= e; i += 4) {
        uint4 q0 = GLD(0), q1 = GLD(1), q2 = GLD(2), q3 = GLD(3);
        ACC8(q0); ACC8(q1); ACC8(q2); ACC8(q3);
    }
    for (; i < e; ++i) {
        uint4 q0 = GLD(0);
        ACC8(q0);
    }
    {   // self-loop message
        uint4 sq = tsq[((size_t)v << 1) + p];
        ACC8(sq);
    }
    const float dv = dinv[v];
    const float4 bA = ((const float4*)b1)[2 * p];
    const float4 bB = ((const float4*)b1)[2 * p + 1];
    float h[8];
    h[0] = fmaxf(fmaf(dv, a0, bA.x), 0.f);
    h[1] = fmaxf(fmaf(dv, a1, bA.y), 0.f);
    h[2] = fmaxf(fmaf(dv, a2, bA.z), 0.f);
    h[3] = fmaxf(fmaf(dv, a3, bA.w), 0.f);
    h[4] = fmaxf(fmaf(dv, a4, bB.x), 0.f);
    h[5] = fmaxf(fmaf(dv, a5, bB.y), 0.f);
    h[6] = fmaxf(fmaf(dv, a6, bB.z), 0.f);
    h[7] = fmaxf(fmaf(dv, a7, bB.w), 0.f);
    // h @ W2 : lane p holds input+output channels 8p..8p+7
    const int my = p * 8, ot = (1 - p) * 8;
    float o[8];
    #pragma unroll
    for (int c = 0; c < 8; ++c) o[c] = 0.f;
    #pragma unroll
    for (int j = 0; j < 8; ++j) {
        float hm = h[j];
        float ho = __shfl_xor(h[j], 1);
        #pragma unroll
        for (int c = 0; c < 8; ++c) {
            o[c] = fmaf(hm, w2s[(my + j) * 16 + my + c],
                   fmaf(ho, w2s[(ot + j) * 16 + my + c], o[c]));
        }
    }
    union { __half hh[8]; uint4 u; } ov;
    #pragma unroll
    for (int c = 0; c < 8; ++c) ov.hh[c] = __float2half(dv * o[c]);
    ts2q[((size_t)v << 1) + p] = ov.u;
}

// ---- Layer-2 aggregation: 2 lanes/node, uint4, 16-deep; epilogue bias ----
__global__ __launch_bounds__(512) void pGat2(
    const unsigned int* __restrict__ ebuf2, const int* __restrict__ start,
    const int* __restrict__ gcur,
    const uint4* __restrict__ tsq, const float* __restrict__ dinv,
    const float* __restrict__ b2, uint4* __restrict__ h2q, int N) {
    const int tid = threadIdx.x;
    const int p = tid & 1;
    const int v = blockIdx.x * 256 + (tid >> 1);
    if (v >= N) return;
    const int s = start[v];
    const int k = v >> BSH;
    const bool lastv = (((v + 1) & (BSZ - 1)) == 0) || (v + 1 >= N);
    const int e = lastv ? (k * CAPB + gcur[k]) : start[v + 1];
    float a0 = 0.f, a1 = 0.f, a2 = 0.f, a3 = 0.f, a4 = 0.f, a5 = 0.f, a6 = 0.f, a7 = 0.f;
    int i = s;
    for (; i + 16 <= e; i += 16) {
        uint4 q0 = GLD(0),  q1 = GLD(1),  q2 = GLD(2),  q3 = GLD(3);
        uint4 q4 = GLD(4),  q5 = GLD(5),  q6 = GLD(6),  q7 = GLD(7);
        uint4 q8 = GLD(8),  q9 = GLD(9),  qa = GLD(10), qb = GLD(11);
        uint4 qc = GLD(12), qd = GLD(13), qe = GLD(14), qf = GLD(15);
        ACC8(q0); ACC8(q1); ACC8(q2); ACC8(q3);
        ACC8(q4); ACC8(q5); ACC8(q6); ACC8(q7);
        ACC8(q8); ACC8(q9); ACC8(qa); ACC8(qb);
        ACC8(qc); ACC8(qd); ACC8(qe); ACC8(qf);
    }
    for (; i + 8 <= e; i += 8) {
        uint4 q0 = GLD(0), q1 = GLD(1), q2 = GLD(2), q3 = GLD(3);
        uint4 q4 = GLD(4), q5 = GLD(5), q6 = GLD(6), q7 = GLD(7);
        ACC8(q0); ACC8(q1); ACC8(q2); ACC8(q3);
        ACC8(q4); ACC8(q5); ACC8(q6); ACC8(q7);
    }
    for (; i + 4 <= e; i += 4) {
        uint4 q0 = GLD(0), q1 = GLD(1), q2 = GLD(2), q3 = GLD(3);
        ACC8(q0); ACC8(q1); ACC8(q2); ACC8(q3);
    }
    for (; i < e; ++i) {
        uint4 q0 = GLD(0);
        ACC8(q0);
    }
    {
        uint4 sq = tsq[((size_t)v << 1) + p];
        ACC8(sq);
    }
    const float dv = dinv[v];
    const float4 bA = ((const float4*)b2)[2 * p];
    const float4 bB = ((const float4*)b2)[2 * p + 1];
    union { __half hh[8]; uint4 u; } ov;
    ov.hh[0] = __float2half(fmaf(dv, a0, bA.x));
    ov.hh[1] = __float2half(fmaf(dv, a1, bA.y));
    ov.hh[2] = __float2half(fmaf(dv, a2, bA.z));
    ov.hh[3] = __float2half(fmaf(dv, a3, bA.w));
    ov.hh[4] = __float2half(fmaf(dv, a4, bB.x));
    ov.hh[5] = __float2half(fmaf(dv, a5, bB.y));
    ov.hh[6] = __float2half(fmaf(dv, a6, bB.z));
    ov.hh[7] = __float2half(fmaf(dv, a7, bB.w));
    h2q[((size_t)v << 1) + p] = ov.u;
}

// ---- Edge scores (R8/R10-proven: 1 edge/thread, no NT) ----
__global__ void k_score(const int* __restrict__ row, const int* __restrict__ col,
                        const __half* __restrict__ h2h, float* __restrict__ out, int E) {
    int e = blockIdx.x * 256 + threadIdx.x;
    if (e < E) {
        union { uint4 u[2]; __half2 h[8]; } a, b;
        const uint4* pa = (const uint4*)(h2h + (size_t)row[e] * 16);
        const uint4* pb = (const uint4*)(h2h + (size_t)col[e] * 16);
        a.u[0] = pa[0]; a.u[1] = pa[1];
        b.u[0] = pb[0]; b.u[1] = pb[1];
        float d = 0.f;
        #pragma unroll
        for (int i = 0; i < 8; ++i) {
            float2 fa = __half22float2(a.h[i]);
            float2 fb = __half22float2(b.h[i]);
            d = fmaf(fa.x, fb.x, fmaf(fa.y, fb.y, d));
        }
        out[e] = 1.0f / (1.0f + __expf(-d));
    }
}

// ---------------- Fallback (R2 atomic path) ----------------
__global__ void k_countf(const int* __restrict__ col, float* __restrict__ deg, int E) {
    int e = blockIdx.x * 256 + threadIdx.x;
    if (e < E) atomicAdd(&deg[col[e]], 1.0f);
}
__global__ void k_dinvf(float* __restrict__ dinv, int N) {
    int v = blockIdx.x * 256 + threadIdx.x;
    if (v < N) dinv[v] = rsqrtf(dinv[v] + 1.0f);
}
__global__ __launch_bounds__(256) void k_gemm1f(
    const float* __restrict__ x, const float* __restrict__ W1,
    const float* __restrict__ dinv, float* __restrict__ ts, int N) {
    __shared__ float wsT[16 * 132];
    const int tid = threadIdx.x;
    for (int idx = tid; idx < 2048; idx += 256) {
        int k = idx >> 4, c = idx & 15;
        wsT[c * 132 + k] = W1[idx];
    }
    __syncthreads();
    const int n = blockIdx.x * 256 + tid;
    if (n >= N) return;
    const float4* xr = (const float4*)(x + (size_t)n * 128);
    float acc[16];
    #pragma unroll
    for (int c = 0; c < 16; ++c) acc[c] = 0.f;
    for (int k4 = 0; k4 < 32; ++k4) {
        float4 a = xr[k4];
        #pragma unroll
        for (int c = 0; c < 16; ++c) {
            const float4 w = *(const float4*)&wsT[c * 132 + k4 * 4];
            acc[c] = fmaf(a.x, w.x, fmaf(a.y, w.y, fmaf(a.z, w.z, fmaf(a.w, w.w, acc[c]))));
        }
    }
    float dv = dinv[n];
    float4* o = (float4*)(ts + (size_t)n * 16);
    #pragma unroll
    for (int q = 0; q < 4; ++q)
        o[q] = make_float4(acc[4*q] * dv, acc[4*q+1] * dv, acc[4*q+2] * dv, acc[4*q+3] * dv);
}
__global__ void k_scatter(const int* __restrict__ row, const int* __restrict__ col,
                          const float* __restrict__ ts, float* __restrict__ acc, int E) {
    int g = blockIdx.x * 256 + threadIdx.x;
    int e = g >> 4, c = g & 15;
    if (e < E) atomicAdd(&acc[(size_t)col[e] * 16 + c], ts[(size_t)row[e] * 16 + c]);
}
__global__ void k_finalize(float* __restrict__ acc, const float* __restrict__ ts,
                           const float* __restrict__ dinv, const float* __restrict__ b,
                           int N, int relu) {
    int g = blockIdx.x * 256 + threadIdx.x;
    int v = g >> 4, c = g & 15;
    if (v < N) {
        float h = dinv[v] * (acc[g] + ts[g]) + b[c];
        if (relu) h = fmaxf(h, 0.f);
        acc[g] = h;
    }
}
__global__ __launch_bounds__(256) void k_gemm2f(
    const float* __restrict__ h1, const float* __restrict__ W2,
    const float* __restrict__ dinv, float* __restrict__ ts2, int N) {
    __shared__ float hs[16 * 17];
    __shared__ float ws2[256];
    const int tid = threadIdx.x;
    const int base = blockIdx.x * 16;
    if (tid < 64) ((float4*)ws2)[tid] = ((const float4*)W2)[tid];
    if (tid >= 64 && tid < 128) {
        int t2 = tid - 64;
        float4 v4 = ((const float4*)(h1 + (size_t)base * 16))[t2];
        float* d = &hs[(t2 >> 2) * 17 + (t2 & 3) * 4];
        d[0] = v4.x; d[1] = v4.y; d[2] = v4.z; d[3] = v4.w;
    }
    __syncthreads();
    const int r = tid >> 4, c = tid & 15;
    float a = 0.f;
    #pragma unroll
    for (int kk = 0; kk < 16; ++kk) a = fmaf(hs[r * 17 + kk], ws2[kk * 16 + c], a);
    ts2[(size_t)(base + r) * 16 + c] = a * dinv[base + r];
}
__global__ void k_scoref(const int* __restrict__ row, const int* __restrict__ col,
                         const float* __restrict__ h2, float* __restrict__ out, int E) {
    int e = blockIdx.x * 256 + threadIdx.x;
    if (e < E) {
        const float4* a = (const float4*)(h2 + (size_t)row[e] * 16);
        const float4* b = (const float4*)(h2 + (size_t)col[e] * 16);
        float d = 0.f;
        #pragma unroll
        for (int i = 0; i < 4; ++i) {
            float4 u = a[i], v = b[i];
            d += u.x * v.x + u.y * v.y + u.z * v.z + u.w * v.w;
        }
        out[e] = 1.0f / (1.0f + __expf(-d));
    }
}

extern "C" void kernel_launch(void* const* d_in, const int* in_sizes, int n_in,
                              void* d_out, int out_size, void* d_ws, size_t ws_size,
                              hipStream_t stream) {
    const float* x  = (const float*)d_in[0];
    const int*   ei = (const int*)d_in[1];
    const float* W1 = (const float*)d_in[2];
    const float* b1 = (const float*)d_in[3];
    const float* W2 = (const float*)d_in[4];
    const float* b2 = (const float*)d_in[5];

    const int N = in_sizes[0] / 128;   // 100000
    const int E = in_sizes[1] / 2;     // 3200000
    const int* row = ei;
    const int* col = ei + E;
    float* out = (float*)d_out;

    const int NBUK = (N + BSZ - 1) / BSZ;          // 782
    const int CN = (E + MAXCH - 1) / MAXCH;        // 1000 chunks
    const int CH = MAXCH;                          // 3200, multiple of 4
    const int GB = (N + 1023) / 1024;              // 98 gemm blocks

    char* ws = (char*)d_ws;
    size_t off = 0;
    auto alloc = [&](size_t bytes) { void* p = ws + off; off += (bytes + 255) & ~(size_t)255; return p; };
    float*  dinv  = (float*)alloc((size_t)N * 4);
    __half* ts1h  = (__half*)alloc((size_t)N * 32);    // also h2h after pGat1
    __half* ts2h  = (__half*)alloc((size_t)N * 32);
    int*    start = (int*)alloc((size_t)(N + 1) * 4);
    int*    gcur  = (int*)alloc((size_t)NBUK * 4);
    unsigned int* ebuf  = (unsigned int*)alloc((size_t)NBUK * CAPB * 4);   // 25.6 MB
    unsigned int* ebuf2 = (unsigned int*)alloc((size_t)NBUK * CAPB * 4);   // 25.6 MB
    const size_t need = off;    // ~59 MB at N=100k, E=3.2M

    // fixed-capacity guard: uniform input fills buckets to ~CAPB/2 (+-64 sigma)
    if (N <= 131072 && NBUK <= 1024 && CN <= MAXCHUNKS &&
        (size_t)E * 2 <= (size_t)NBUK * CAPB && ws_size >= need) {
        hipMemsetAsync(gcur, 0, (size_t)NBUK * 4, stream);
        pSortG<<<CN + GB, 1024, 0, stream>>>(row, col, gcur, ebuf, x, W1, ts1h,
                                             E, CH, NBUK, N, CN);
        pS2G<<<NBUK, 512, 0, stream>>>(ebuf, gcur, ebuf2, dinv, start, ts1h, N);
        pGat1<<<(N + 255) / 256, 512, 0, stream>>>(ebuf2, start, gcur, (const uint4*)ts1h,
                                                   dinv, b1, W2, (uint4*)ts2h, N);
        __half* h2h = ts1h;   // ts1h dead after pGat1
        pGat2<<<(N + 255) / 256, 512, 0, stream>>>(ebuf2, start, gcur, (const uint4*)ts2h,
                                                   dinv, b2, (uint4*)h2h, N);
        k_score<<<(E + 255) / 256, 256, 0, stream>>>(row, col, h2h, out, E);
    } else {
        // R2 fallback, fp32 buffers carved independently
        float* dinvF = (float*)ws;
        float* ts1F  = (float*)(ws + (size_t)N * 4);
        float* ts2F  = (float*)(ws + (size_t)N * 4 + (size_t)N * 64);
        hipMemsetAsync(dinvF, 0, (size_t)N * 4, stream);
        hipMemsetAsync(ts2F, 0, (size_t)N * 64, stream);
        k_countf<<<(E + 255) / 256, 256, 0, stream>>>(col, dinvF, E);
        k_dinvf<<<(N + 255) / 256, 256, 0, stream>>>(dinvF, N);
        k_gemm1f<<<(N + 255) / 256, 256, 0, stream>>>(x, W1, dinvF, ts1F, N);
        k_scatter<<<(E * 16) / 256, 256, 0, stream>>>(row, col, ts1F, ts2F, E);
        k_finalize<<<(N * 16 + 255) / 256, 256, 0, stream>>>(ts2F, ts1F, dinvF, b1, N, 1);
        k_gemm2f<<<N / 16, 256, 0, stream>>>(ts2F, W2, dinvF, ts1F, N);
        hipMemsetAsync(ts2F, 0, (size_t)N * 64, stream);
        k_scatter<<<(E * 16) / 256, 256, 0, stream>>>(row, col, ts1F, ts2F, E);
        k_finalize<<<(N * 16 + 255) / 256, 256, 0, stream>>>(ts2F, ts1F, dinvF, b2, N, 0);
        k_scoref<<<(E + 255) / 256, 256, 0, stream>>>(row, col, ts2F, out, E);
    }
}

// Round 9
// 252.912 us; speedup vs baseline: 1.0827x; 1.0827x over previous
//
#include <hip/hip_runtime.h>
#include <hip/hip_bf16.h>
#include <hip/hip_fp16.h>
#include <math.h>

// GCN link prediction. R20 = R18 (best recent config, 256.6us) with ONE
// change: pS2G prefetches its gemm x-rows into registers at kernel ENTRY
// (8x float4/thread, 4 threads/node interleaved-K), so the 51MB x HBM stream
// is in flight underneath the ~20us in-bucket sort instead of serialized
// after it (R18 counters: pS2G 46us at 1.07TB/s = sort then x-stream).
// R19 lessons applied: no role-split mega-kernel (LDS footprint + tail
// scheduling regressed 17us); gather lane-shape stays R11-proven 8-lane
// (2-lane uint4 was neutral -- gathers sit at the L2 scattered-access floor).
//   deg[v] = incount(col==v)+1 ; dinv = rsqrt(deg)
//   ts[v]  = (h[v]@W)*dinv[v]          (fp16 gather tables, L2-resident)
//   h'[c]  = act(dinv[c]*(sum_{e:col=c} ts[row_e] + ts[c]) + b)
//   score  = sigmoid(dot(h2[row], h2[col]))

#define BSH 7
#define BSZ 128            // nodes per bucket -> NBUK = 782 (<= 1024)
#define CAPB 8192          // slots per bucket (2x avg 4092; +60 sigma)
#define RCAP 12            // edge register cache per thread in pS2G (512 thr)
#define MAXCH 3200         // edges per chunk (multiple of 4)
#define MAXCHUNKS 1024

// ---- pSort: chunk histogram -> atomic base grab -> LDS bucket-order ->
//      run writes into fixed-capacity bucket regions (R18-proven) ----
__global__ __launch_bounds__(1024) void pSort(
    const int* __restrict__ row, const int* __restrict__ col,
    int* __restrict__ gcur, unsigned int* __restrict__ ebuf,
    int E, int CH, int NBUK) {
    __shared__ unsigned int se[MAXCH];        // chunk edges, bucket-ordered
    __shared__ unsigned short pk[MAXCH];      // bucket id per LDS slot
    __shared__ int lhist[1024], lbase[1024], lcur[1024], gbase[1024];
    const int t = threadIdx.x, b = blockIdx.x;
    lhist[t] = 0;
    __syncthreads();
    const int s = b * CH, e = min(E, s + CH);
    const int cnt = e - s;
    const int n4 = cnt >> 2;
    const int4* c4 = (const int4*)(col + s);
    const int4* r4 = (const int4*)(row + s);
    for (int i = t; i < n4; i += 1024) {
        int4 c = c4[i];
        atomicAdd(&lhist[c.x >> BSH], 1);
        atomicAdd(&lhist[c.y >> BSH], 1);
        atomicAdd(&lhist[c.z >> BSH], 1);
        atomicAdd(&lhist[c.w >> BSH], 1);
    }
    for (int i = (n4 << 2) + t; i < cnt; i += 1024) atomicAdd(&lhist[col[s + i] >> BSH], 1);
    __syncthreads();
    {   // 1024-wide exclusive scan of lhist -> lbase (scratch in lcur)
        int own = lhist[t];
        lcur[t] = own;
        __syncthreads();
        for (int d = 1; d < 1024; d <<= 1) {
            int add = (t >= d) ? lcur[t - d] : 0;
            __syncthreads();
            lcur[t] += add;
            __syncthreads();
        }
        lbase[t] = lcur[t] - own;
        lcur[t] = lbase[t];
        __syncthreads();
        if (t < NBUK) {   // grab this chunk's range in bucket t
            int base = atomicAdd(&gcur[t], lhist[t]);
            gbase[t] = t * CAPB + base - lbase[t];
        }
    }
    __syncthreads();
    // placement into LDS (bucket-ordered)
    for (int i = t; i < n4; i += 1024) {
        int4 c = c4[i];
        int4 r = r4[i];
        int k0 = c.x >> BSH, p0 = atomicAdd(&lcur[k0], 1);
        se[p0] = ((unsigned int)(c.x & (BSZ - 1)) << 17) | (unsigned int)r.x; pk[p0] = (unsigned short)k0;
        int k1 = c.y >> BSH, p1 = atomicAdd(&lcur[k1], 1);
        se[p1] = ((unsigned int)(c.y & (BSZ - 1)) << 17) | (unsigned int)r.y; pk[p1] = (unsigned short)k1;
        int k2 = c.z >> BSH, p2 = atomicAdd(&lcur[k2], 1);
        se[p2] = ((unsigned int)(c.z & (BSZ - 1)) << 17) | (unsigned int)r.z; pk[p2] = (unsigned short)k2;
        int k3 = c.w >> BSH, p3 = atomicAdd(&lcur[k3], 1);
        se[p3] = ((unsigned int)(c.w & (BSZ - 1)) << 17) | (unsigned int)r.w; pk[p3] = (unsigned short)k3;
    }
    for (int i = (n4 << 2) + t; i < cnt; i += 1024) {
        int c = col[s + i], r = row[s + i];
        int k = c >> BSH, p = atomicAdd(&lcur[k], 1);
        se[p] = ((unsigned int)(c & (BSZ - 1)) << 17) | (unsigned int)r; pk[p] = (unsigned short)k;
    }
    __syncthreads();
    // write-out: consecutive LDS slots in a bucket -> consecutive global
    for (int i = t; i < cnt; i += 1024) {
        int k = pk[i];
        ebuf[gbase[k] + i] = se[i];
    }
}

// One interleaved-K gemm step over a prefetched float4 register.
#define GEMMSTEP(J, A) do {                                                  \
    const int kk_ = q + 4 * (J);                                             \
    _Pragma("unroll")                                                        \
    for (int c = 0; c < 16; ++c) {                                           \
        const float4 w_ = *(const float4*)&wsT[c * 132 + kk_ * 4];           \
        acc[c] = fmaf((A).x, w_.x, fmaf((A).y, w_.y,                         \
                 fmaf((A).z, w_.z, fmaf((A).w, w_.w, acc[c]))));             \
    }                                                                        \
} while (0)

// ---- pS2G: EARLY x prefetch (regs) -> in-bucket counting sort (register-
//      cached edges) -> dinv + CSR start -> fused GEMM1 epilogue ----
__global__ __launch_bounds__(512) void pS2G(
    const unsigned int* __restrict__ ebuf, const int* __restrict__ gcur,
    const float* __restrict__ x, const float* __restrict__ W1,
    unsigned int* __restrict__ ebuf2, float* __restrict__ dinv,
    int* __restrict__ start, __half* __restrict__ ts, int N) {
    __shared__ int h[BSZ], sc[BSZ], cur[BSZ];
    __shared__ float wsT[16 * 132];
    const int t = threadIdx.x, k = blockIdx.x;
    const int u = t >> 2, q = t & 3;           // gemm role: 4 threads/node
    const int vg = (k << BSH) + u;
    // ---- early x prefetch: issued NOW, consumed after the sort (~20us) ----
    float4 xr0, xr1, xr2, xr3, xr4, xr5, xr6, xr7;
    if (vg < N) {
        const float4* xp = (const float4*)(x + (size_t)vg * 128);
        xr0 = xp[q];      xr1 = xp[q + 4];  xr2 = xp[q + 8];  xr3 = xp[q + 12];
        xr4 = xp[q + 16]; xr5 = xp[q + 20]; xr6 = xp[q + 24]; xr7 = xp[q + 28];
    }
    if (t < BSZ) h[t] = 0;
    // stage W1 transposed: wsT[c*132+kk] = W1[kk*16+c]
    for (int idx = t; idx < 2048; idx += 512) {
        int kk = idx >> 4, c = idx & 15;
        wsT[c * 132 + kk] = W1[idx];
    }
    __syncthreads();
    const int s = k * CAPB, e = s + gcur[k];
    const int cnt = e - s;
    unsigned int r[RCAP];
    const bool fits = (cnt <= 512 * RCAP);
    if (fits) {
        int nr = 0;
        for (int i = s + t; i < e; i += 512) {
            unsigned int w = ebuf[i];
            r[nr++] = w;
            atomicAdd(&h[w >> 17], 1);
        }
    } else {
        for (int i = s + t; i < e; i += 512) atomicAdd(&h[ebuf[i] >> 17], 1);
    }
    __syncthreads();
    if (t < BSZ) sc[t] = h[t];
    __syncthreads();
    for (int d = 1; d < BSZ; d <<= 1) {
        int add = (t < BSZ && t >= d) ? sc[t - d] : 0;
        __syncthreads();
        if (t < BSZ) sc[t] += add;
        __syncthreads();
    }
    if (t < BSZ) {
        cur[t] = sc[t] - h[t];             // exclusive scan
        const int v = (k << BSH) + t;
        if (v < N) {
            dinv[v] = rsqrtf((float)h[t] + 1.0f);
            start[v] = s + cur[t];
        }
    }
    __syncthreads();
    if (fits) {
        int nr = 0;
        for (int i = s + t; i < e; i += 512) {
            unsigned int w = r[nr++];
            int p = atomicAdd(&cur[w >> 17], 1);
            ebuf2[s + p] = w;
        }
    } else {
        for (int i = s + t; i < e; i += 512) {
            unsigned int w = ebuf[i];
            int p = atomicAdd(&cur[w >> 17], 1);
            ebuf2[s + p] = w;
        }
    }
    // ---- fused GEMM1 epilogue: consumes the prefetched xr0..xr7.
    //      h[] is stable after the histogram barrier (only cur[] mutates) ----
    if (vg >= N) return;
    const float dv = rsqrtf((float)h[u] + 1.0f);
    float acc[16];
    #pragma unroll
    for (int c = 0; c < 16; ++c) acc[c] = 0.f;
    GEMMSTEP(0, xr0); GEMMSTEP(1, xr1); GEMMSTEP(2, xr2); GEMMSTEP(3, xr3);
    GEMMSTEP(4, xr4); GEMMSTEP(5, xr5); GEMMSTEP(6, xr6); GEMMSTEP(7, xr7);
    #pragma unroll
    for (int c = 0; c < 16; ++c) {
        acc[c] += __shfl_xor(acc[c], 1);
        acc[c] += __shfl_xor(acc[c], 2);
    }
    union { __half h4[4]; uint2 u2; } o;
    #pragma unroll
    for (int c = 0; c < 4; ++c) o.h4[c] = __float2half(acc[q * 4 + c] * dv);
    ((uint2*)(ts + (size_t)vg * 16))[q] = o.u2;   // q lanes write 8B each, 32B/node
}

// ---- Layer-1 aggregation: 8 lanes/node, 8-deep unrolled CSR gather (no NT),
//      fused bias/ReLU + 16x16 W2 via width-8 shuffles (R11-proven) ----
__global__ __launch_bounds__(256) void pGat1(
    const unsigned int* __restrict__ ebuf2, const int* __restrict__ start,
    const int* __restrict__ gcur,
    const __half2* __restrict__ tsv, const float* __restrict__ dinv,
    const float* __restrict__ b1, const float* __restrict__ W2,
    __half2* __restrict__ ts2v, int N) {
    __shared__ float w2s[256];
    const int tid = threadIdx.x;
    w2s[tid] = W2[tid];
    __syncthreads();
    const int l = tid & 7;                 // channel pair: c0=2l, c1=2l+1
    const int v = blockIdx.x * 32 + (tid >> 3);
    if (v >= N) return;
    const int s = start[v];
    const int k = v >> BSH;
    const bool lastv = (((v + 1) & (BSZ - 1)) == 0) || (v + 1 >= N);
    const int e = lastv ? (k * CAPB + gcur[k]) : start[v + 1];
    float sx = 0.f, sy = 0.f;
    int i = s;
    for (; i + 8 <= e; i += 8) {
        unsigned int w0 = ebuf2[i],     w1 = ebuf2[i + 1];
        unsigned int w2 = ebuf2[i + 2], w3 = ebuf2[i + 3];
        unsigned int w4 = ebuf2[i + 4], w5 = ebuf2[i + 5];
        unsigned int w6 = ebuf2[i + 6], w7 = ebuf2[i + 7];
        float2 f0 = __half22float2(tsv[(size_t)(w0 & 0x1FFFF) * 8 + l]);
        float2 f1 = __half22float2(tsv[(size_t)(w1 & 0x1FFFF) * 8 + l]);
        float2 f2 = __half22float2(tsv[(size_t)(w2 & 0x1FFFF) * 8 + l]);
        float2 f3 = __half22float2(tsv[(size_t)(w3 & 0x1FFFF) * 8 + l]);
        float2 f4 = __half22float2(tsv[(size_t)(w4 & 0x1FFFF) * 8 + l]);
        float2 f5 = __half22float2(tsv[(size_t)(w5 & 0x1FFFF) * 8 + l]);
        float2 f6 = __half22float2(tsv[(size_t)(w6 & 0x1FFFF) * 8 + l]);
        float2 f7 = __half22float2(tsv[(size_t)(w7 & 0x1FFFF) * 8 + l]);
        sx += ((f0.x + f1.x) + (f2.x + f3.x)) + ((f4.x + f5.x) + (f6.x + f7.x));
        sy += ((f0.y + f1.y) + (f2.y + f3.y)) + ((f4.y + f5.y) + (f6.y + f7.y));
    }
    for (; i + 4 <= e; i += 4) {
        unsigned int w0 = ebuf2[i],     w1 = ebuf2[i + 1];
        unsigned int w2 = ebuf2[i + 2], w3 = ebuf2[i + 3];
        float2 f0 = __half22float2(tsv[(size_t)(w0 & 0x1FFFF) * 8 + l]);
        float2 f1 = __half22float2(tsv[(size_t)(w1 & 0x1FFFF) * 8 + l]);
        float2 f2 = __half22float2(tsv[(size_t)(w2 & 0x1FFFF) * 8 + l]);
        float2 f3 = __half22float2(tsv[(size_t)(w3 & 0x1FFFF) * 8 + l]);
        sx += (f0.x + f1.x) + (f2.x + f3.x);
        sy += (f0.y + f1.y) + (f2.y + f3.y);
    }
    for (; i < e; ++i) {
        unsigned int w = ebuf2[i];
        float2 f = __half22float2(tsv[(size_t)(w & 0x1FFFF) * 8 + l]);
        sx += f.x; sy += f.y;
    }
    const float dv = dinv[v];
    float2 sf = __half22float2(tsv[(size_t)v * 8 + l]);
    float hx = fmaxf(dv * (sx + sf.x) + b1[2 * l],     0.f);
    float hy = fmaxf(dv * (sy + sf.y) + b1[2 * l + 1], 0.f);
    float ox = 0.f, oy = 0.f;
    #pragma unroll
    for (int j = 0; j < 8; ++j) {
        float ax = __shfl(hx, j, 8);       // channel 2j
        float ay = __shfl(hy, j, 8);       // channel 2j+1
        ox = fmaf(ax, w2s[(2 * j) * 16 + 2 * l],     fmaf(ay, w2s[(2 * j + 1) * 16 + 2 * l],     ox));
        oy = fmaf(ax, w2s[(2 * j) * 16 + 2 * l + 1], fmaf(ay, w2s[(2 * j + 1) * 16 + 2 * l + 1], oy));
    }
    ts2v[(size_t)v * 8 + l] = __halves2half2(__float2half(dv * ox), __float2half(dv * oy));
}

// ---- Layer-2 aggregation: 8 lanes/node, 8-deep unrolled CSR gather + bias ----
__global__ __launch_bounds__(256) void pGat2(
    const unsigned int* __restrict__ ebuf2, const int* __restrict__ start,
    const int* __restrict__ gcur,
    const __half2* __restrict__ tsv, const float* __restrict__ dinv,
    const float* __restrict__ b2, __half2* __restrict__ h2v, int N) {
    const int tid = threadIdx.x;
    const int l = tid & 7;
    const int v = blockIdx.x * 32 + (tid >> 3);
    if (v >= N) return;
    const int s = start[v];
    const int k = v >> BSH;
    const bool lastv = (((v + 1) & (BSZ - 1)) == 0) || (v + 1 >= N);
    const int e = lastv ? (k * CAPB + gcur[k]) : start[v + 1];
    float sx = 0.f, sy = 0.f;
    int i = s;
    for (; i + 8 <= e; i += 8) {
        unsigned int w0 = ebuf2[i],     w1 = ebuf2[i + 1];
        unsigned int w2 = ebuf2[i + 2], w3 = ebuf2[i + 3];
        unsigned int w4 = ebuf2[i + 4], w5 = ebuf2[i + 5];
        unsigned int w6 = ebuf2[i + 6], w7 = ebuf2[i + 7];
        float2 f0 = __half22float2(tsv[(size_t)(w0 & 0x1FFFF) * 8 + l]);
        float2 f1 = __half22float2(tsv[(size_t)(w1 & 0x1FFFF) * 8 + l]);
        float2 f2 = __half22float2(tsv[(size_t)(w2 & 0x1FFFF) * 8 + l]);
        float2 f3 = __half22float2(tsv[(size_t)(w3 & 0x1FFFF) * 8 + l]);
        float2 f4 = __half22float2(tsv[(size_t)(w4 & 0x1FFFF) * 8 + l]);
        float2 f5 = __half22float2(tsv[(size_t)(w5 & 0x1FFFF) * 8 + l]);
        float2 f6 = __half22float2(tsv[(size_t)(w6 & 0x1FFFF) * 8 + l]);
        float2 f7 = __half22float2(tsv[(size_t)(w7 & 0x1FFFF) * 8 + l]);
        sx += ((f0.x + f1.x) + (f2.x + f3.x)) + ((f4.x + f5.x) + (f6.x + f7.x));
        sy += ((f0.y + f1.y) + (f2.y + f3.y)) + ((f4.y + f5.y) + (f6.y + f7.y));
    }
    for (; i + 4 <= e; i += 4) {
        unsigned int w0 = ebuf2[i],     w1 = ebuf2[i + 1];
        unsigned int w2 = ebuf2[i + 2], w3 = ebuf2[i + 3];
        float2 f0 = __half22float2(tsv[(size_t)(w0 & 0x1FFFF) * 8 + l]);
        float2 f1 = __half22float2(tsv[(size_t)(w1 & 0x1FFFF) * 8 + l]);
        float2 f2 = __half22float2(tsv[(size_t)(w2 & 0x1FFFF) * 8 + l]);
        float2 f3 = __half22float2(tsv[(size_t)(w3 & 0x1FFFF) * 8 + l]);
        sx += (f0.x + f1.x) + (f2.x + f3.x);
        sy += (f0.y + f1.y) + (f2.y + f3.y);
    }
    for (; i < e; ++i) {
        unsigned int w = ebuf2[i];
        float2 f = __half22float2(tsv[(size_t)(w & 0x1FFFF) * 8 + l]);
        sx += f.x; sy += f.y;
    }
    float2 sf = __half22float2(tsv[(size_t)v * 8 + l]);
    const float dv = dinv[v];
    h2v[(size_t)v * 8 + l] = __halves2half2(
        __float2half(dv * (sx + sf.x) + b2[2 * l]),
        __float2half(dv * (sy + sf.y) + b2[2 * l + 1]));
}

// ---- Edge scores (R8/R10-proven: 1 edge/thread, no NT) ----
__global__ void k_score(const int* __restrict__ row, const int* __restrict__ col,
                        const __half* __restrict__ h2h, float* __restrict__ out, int E) {
    int e = blockIdx.x * 256 + threadIdx.x;
    if (e < E) {
        union { uint4 u[2]; __half2 h[8]; } a, b;
        const uint4* pa = (const uint4*)(h2h + (size_t)row[e] * 16);
        const uint4* pb = (const uint4*)(h2h + (size_t)col[e] * 16);
        a.u[0] = pa[0]; a.u[1] = pa[1];
        b.u[0] = pb[0]; b.u[1] = pb[1];
        float d = 0.f;
        #pragma unroll
        for (int i = 0; i < 8; ++i) {
            float2 fa = __half22float2(a.h[i]);
            float2 fb = __half22float2(b.h[i]);
            d = fmaf(fa.x, fb.x, fmaf(fa.y, fb.y, d));
        }
        out[e] = 1.0f / (1.0f + __expf(-d));
    }
}

// ---------------- Fallback (R2 atomic path) ----------------
__global__ void k_countf(const int* __restrict__ col, float* __restrict__ deg, int E) {
    int e = blockIdx.x * 256 + threadIdx.x;
    if (e < E) atomicAdd(&deg[col[e]], 1.0f);
}
__global__ void k_dinvf(float* __restrict__ dinv, int N) {
    int v = blockIdx.x * 256 + threadIdx.x;
    if (v < N) dinv[v] = rsqrtf(dinv[v] + 1.0f);
}
__global__ __launch_bounds__(256) void k_gemm1f(
    const float* __restrict__ x, const float* __restrict__ W1,
    const float* __restrict__ dinv, float* __restrict__ ts, int N) {
    __shared__ float wsT[16 * 132];
    const int tid = threadIdx.x;
    for (int idx = tid; idx < 2048; idx += 256) {
        int k = idx >> 4, c = idx & 15;
        wsT[c * 132 + k] = W1[idx];
    }
    __syncthreads();
    const int n = blockIdx.x * 256 + tid;
    if (n >= N) return;
    const float4* xr = (const float4*)(x + (size_t)n * 128);
    float acc[16];
    #pragma unroll
    for (int c = 0; c < 16; ++c) acc[c] = 0.f;
    for (int k4 = 0; k4 < 32; ++k4) {
        float4 a = xr[k4];
        #pragma unroll
        for (int c = 0; c < 16; ++c) {
            const float4 w = *(const float4*)&wsT[c * 132 + k4 * 4];
            acc[c] = fmaf(a.x, w.x, fmaf(a.y, w.y, fmaf(a.z, w.z, fmaf(a.w, w.w, acc[c]))));
        }
    }
    float dv = dinv[n];
    float4* o = (float4*)(ts + (size_t)n * 16);
    #pragma unroll
    for (int q = 0; q < 4; ++q)
        o[q] = make_float4(acc[4*q] * dv, acc[4*q+1] * dv, acc[4*q+2] * dv, acc[4*q+3] * dv);
}
__global__ void k_scatter(const int* __restrict__ row, const int* __restrict__ col,
                          const float* __restrict__ ts, float* __restrict__ acc, int E) {
    int g = blockIdx.x * 256 + threadIdx.x;
    int e = g >> 4, c = g & 15;
    if (e < E) atomicAdd(&acc[(size_t)col[e] * 16 + c], ts[(size_t)row[e] * 16 + c]);
}
__global__ void k_finalize(float* __restrict__ acc, const float* __restrict__ ts,
                           const float* __restrict__ dinv, const float* __restrict__ b,
                           int N, int relu) {
    int g = blockIdx.x * 256 + threadIdx.x;
    int v = g >> 4, c = g & 15;
    if (v < N) {
        float h = dinv[v] * (acc[g] + ts[g]) + b[c];
        if (relu) h = fmaxf(h, 0.f);
        acc[g] = h;
    }
}
__global__ __launch_bounds__(256) void k_gemm2f(
    const float* __restrict__ h1, const float* __restrict__ W2,
    const float* __restrict__ dinv, float* __restrict__ ts2, int N) {
    __shared__ float hs[16 * 17];
    __shared__ float ws2[256];
    const int tid = threadIdx.x;
    const int base = blockIdx.x * 16;
    if (tid < 64) ((float4*)ws2)[tid] = ((const float4*)W2)[tid];
    if (tid >= 64 && tid < 128) {
        int t2 = tid - 64;
        float4 v4 = ((const float4*)(h1 + (size_t)base * 16))[t2];
        float* d = &hs[(t2 >> 2) * 17 + (t2 & 3) * 4];
        d[0] = v4.x; d[1] = v4.y; d[2] = v4.z; d[3] = v4.w;
    }
    __syncthreads();
    const int r = tid >> 4, c = tid & 15;
    float a = 0.f;
    #pragma unroll
    for (int kk = 0; kk < 16; ++kk) a = fmaf(hs[r * 17 + kk], ws2[kk * 16 + c], a);
    ts2[(size_t)(base + r) * 16 + c] = a * dinv[base + r];
}
__global__ void k_scoref(const int* __restrict__ row, const int* __restrict__ col,
                         const float* __restrict__ h2, float* __restrict__ out, int E) {
    int e = blockIdx.x * 256 + threadIdx.x;
    if (e < E) {
        const float4* a = (const float4*)(h2 + (size_t)row[e] * 16);
        const float4* b = (const float4*)(h2 + (size_t)col[e] * 16);
        float d = 0.f;
        #pragma unroll
        for (int i = 0; i < 4; ++i) {
            float4 u = a[i], v = b[i];
            d += u.x * v.x + u.y * v.y + u.z * v.z + u.w * v.w;
        }
        out[e] = 1.0f / (1.0f + __expf(-d));
    }
}

extern "C" void kernel_launch(void* const* d_in, const int* in_sizes, int n_in,
                              void* d_out, int out_size, void* d_ws, size_t ws_size,
                              hipStream_t stream) {
    const float* x  = (const float*)d_in[0];
    const int*   ei = (const int*)d_in[1];
    const float* W1 = (const float*)d_in[2];
    const float* b1 = (const float*)d_in[3];
    const float* W2 = (const float*)d_in[4];
    const float* b2 = (const float*)d_in[5];

    const int N = in_sizes[0] / 128;   // 100000
    const int E = in_sizes[1] / 2;     // 3200000
    const int* row = ei;
    const int* col = ei + E;
    float* out = (float*)d_out;

    const int NBUK = (N + BSZ - 1) / BSZ;          // 782
    const int CN = (E + MAXCH - 1) / MAXCH;        // 1000 chunks
    const int CH = MAXCH;                          // 3200, multiple of 4

    char* ws = (char*)d_ws;
    size_t off = 0;
    auto alloc = [&](size_t bytes) { void* p = ws + off; off += (bytes + 255) & ~(size_t)255; return p; };
    float*  dinv  = (float*)alloc((size_t)N * 4);
    __half* ts1h  = (__half*)alloc((size_t)N * 32);    // also h2h after pGat1
    __half* ts2h  = (__half*)alloc((size_t)N * 32);
    int*    start = (int*)alloc((size_t)(N + 1) * 4);
    int*    gcur  = (int*)alloc((size_t)NBUK * 4);
    unsigned int* ebuf  = (unsigned int*)alloc((size_t)NBUK * CAPB * 4);   // 25.6 MB
    unsigned int* ebuf2 = (unsigned int*)alloc((size_t)NBUK * CAPB * 4);   // 25.6 MB
    const size_t need = off;    // ~59 MB at N=100k, E=3.2M

    // fixed-capacity guard: uniform input fills buckets to ~CAPB/2 (+-64 sigma)
    if (N <= 131072 && NBUK <= 1024 && CN <= MAXCHUNKS &&
        (size_t)E * 2 <= (size_t)NBUK * CAPB && ws_size >= need) {
        hipMemsetAsync(gcur, 0, (size_t)NBUK * 4, stream);
        pSort<<<CN, 1024, 0, stream>>>(row, col, gcur, ebuf, E, CH, NBUK);
        pS2G<<<NBUK, 512, 0, stream>>>(ebuf, gcur, x, W1, ebuf2, dinv, start, ts1h, N);
        pGat1<<<(N + 31) / 32, 256, 0, stream>>>(ebuf2, start, gcur, (const __half2*)ts1h,
                                                 dinv, b1, W2, (__half2*)ts2h, N);
        __half* h2h = ts1h;   // ts1h dead after pGat1
        pGat2<<<(N + 31) / 32, 256, 0, stream>>>(ebuf2, start, gcur, (const __half2*)ts2h,
                                                 dinv, b2, (__half2*)h2h, N);
        k_score<<<(E + 255) / 256, 256, 0, stream>>>(row, col, h2h, out, E);
    } else {
        // R2 fallback, fp32 buffers carved independently
        float* dinvF = (float*)ws;
        float* ts1F  = (float*)(ws + (size_t)N * 4);
        float* ts2F  = (float*)(ws + (size_t)N * 4 + (size_t)N * 64);
        hipMemsetAsync(dinvF, 0, (size_t)N * 4, stream);
        hipMemsetAsync(ts2F, 0, (size_t)N * 64, stream);
        k_countf<<<(E + 255) / 256, 256, 0, stream>>>(col, dinvF, E);
        k_dinvf<<<(N + 255) / 256, 256, 0, stream>>>(dinvF, N);
        k_gemm1f<<<(N + 255) / 256, 256, 0, stream>>>(x, W1, dinvF, ts1F, N);
        k_scatter<<<(E * 16) / 256, 256, 0, stream>>>(row, col, ts1F, ts2F, E);
        k_finalize<<<(N * 16 + 255) / 256, 256, 0, stream>>>(ts2F, ts1F, dinvF, b1, N, 1);
        k_gemm2f<<<N / 16, 256, 0, stream>>>(ts2F, W2, dinvF, ts1F, N);
        hipMemsetAsync(ts2F, 0, (size_t)N * 64, stream);
        k_scatter<<<(E * 16) / 256, 256, 0, stream>>>(row, col, ts1F, ts2F, E);
        k_finalize<<<(N * 16 + 255) / 256, 256, 0, stream>>>(ts2F, ts1F, dinvF, b2, N, 0);
        k_scoref<<<(E + 255) / 256, 256, 0, stream>>>(row, col, ts2F, out, E);
    }
}